// Round 8
// baseline (767.821 us; speedup 1.0000x reference)
//
#include <hip/hip_runtime.h>
#include <hip/hip_bf16.h>
#include <hip/hip_fp8.h>

// v8: fp8 grid tables in ws (R6-proven) + weights pre-packed bf16 into ws.
// Fused kernel: 512 thr / 256 pts per block, LDS = activations only (36.9KB)
// -> 4 blocks/CU (32 waves), independent blocks overlap hash & MLP phases.
// Hash: R6-verbatim (2 thr/pt, 8 levels each, 16-gather batches).
// MLP: R0/R6-verbatim 32-row/wave mlp_layer; W/bias fragments from ws-global.
// Fallback (ws too small): R6's full-LDS f32-grid kernel (proven).

#define TBL   524288      // T = 1<<19
#define TMASK (TBL - 1)
#define MPB   256         // points per block (fused kernel)
#define NTHR  512

#define GRID_SHORTS (16 * TBL)          // fp8 pair entries
#define GRID_BYTES  (GRID_SHORTS * 2)   // 16 MB
// short-offsets of packed weights inside ws (after the fp8 grid)
#define OW0 0                            // [64][40] K=32
#define OW1 2560                         // [64][72]
#define OC0 7168                         // [64][72] (cw0 remapped)
#define OC1 11776                        // [64][72]
#define OC2 16384                        // [64][72]
#define OW2 20992                        // [16][72]
#define OC3 22144                        // [16][72]
#define OBF 23296                        // 352 f32 biases (as shorts offset)
#define WS_NEED ((size_t)GRID_BYTES + 48000)

#define FP8_SCALE     1048576.0f          // 2^20
#define FP8_INV_SCALE 9.5367431640625e-7f // 2^-20

typedef __bf16 bf16x8 __attribute__((ext_vector_type(8)));
typedef float  f32x4  __attribute__((ext_vector_type(4)));

// floor(16 * 1.3819^l) for l = 0..15 (computed in double; all >=0.04 from integer)
__device__ const float RES_TAB[16] = {
    16.f, 22.f, 30.f, 42.f, 58.f, 80.f, 111.f, 153.f,
    212.f, 294.f, 406.f, 561.f, 775.f, 1072.f, 1481.f, 2047.f
};

__device__ __forceinline__ unsigned short f2bf(float f) {
    __hip_bfloat16 h = __float2bfloat16(f);
    unsigned short u;
    __builtin_memcpy(&u, &h, 2);
    return u;
}
__device__ __forceinline__ unsigned pack2(float a, float b) {
    return (unsigned)f2bf(a) | ((unsigned)f2bf(b) << 16);
}

// ---- fp8 e4m3 (OCP) helpers ----
__device__ __forceinline__ float fp8_dec(unsigned b) {
#if defined(__has_builtin) && __has_builtin(__builtin_amdgcn_cvt_f32_fp8)
    return __builtin_amdgcn_cvt_f32_fp8((int)b, 0);
#else
    const unsigned e = (b >> 3) & 0xF, m = b & 7;
    float v = e ? ldexpf((float)(8 + m), (int)e - 10) : ldexpf((float)m, -9);
    return (b & 0x80) ? -v : v;
#endif
}
__device__ __forceinline__ unsigned short fp8_pair(float a, float b) {
#if defined(__has_builtin) && __has_builtin(__builtin_amdgcn_cvt_pk_fp8_f32)
    return (unsigned short)(__builtin_amdgcn_cvt_pk_fp8_f32(a, b, 0, false) & 0xffff);
#else
    __hip_fp8_e4m3 qa(a), qb(b);
    return (unsigned short)((unsigned)qa.__x | ((unsigned)qb.__x << 8));
#endif
}

// ---------------------------------------------------------------------------
// grid (f32 pairs) -> packed fp8 pairs (scaled by 2^20) in ws.
__global__ void __launch_bounds__(1024) grid_to_fp8(
    const float2* __restrict__ g, unsigned short* __restrict__ o, int n)
{
    const int i = blockIdx.x * 1024 + threadIdx.x;
    if (i < n) {
        const float2 v = g[i];
        o[i] = fp8_pair(v.x * FP8_SCALE, v.y * FP8_SCALE);
    }
}

// Pack all weights (bf16, padded strides, cw0 remapped) + biases (f32) into ws.
__global__ void __launch_bounds__(1024) pack_weights(
    unsigned short* __restrict__ w,
    const float* __restrict__ sw0, const float* __restrict__ sb0,
    const float* __restrict__ sw1, const float* __restrict__ sb1,
    const float* __restrict__ sw2, const float* __restrict__ sb2,
    const float* __restrict__ cw0, const float* __restrict__ cb0,
    const float* __restrict__ cw1, const float* __restrict__ cb1,
    const float* __restrict__ cw2, const float* __restrict__ cb2,
    const float* __restrict__ cw3, const float* __restrict__ cb3)
{
    const int tid = threadIdx.x;
    for (int i = tid; i < 64 * 40; i += 1024) { int n = i / 40, k = i % 40; w[OW0 + i] = f2bf(k < 32 ? sw0[n * 32 + k] : 0.f); }
    for (int i = tid; i < 64 * 72; i += 1024) { int n = i / 72, k = i % 72; w[OW1 + i] = f2bf(k < 64 ? sw1[n * 64 + k] : 0.f); }
    // cw0 is [64][47] over cin order [geo(0..14) | sh(15..30) | lat(31..46)].
    // Our cin layout: k' 0..14 = geo, k' 15..31 = zero, k' 32..47 = sh, k' 48..63 = lat.
    for (int i = tid; i < 64 * 72; i += 1024) {
        int n = i / 72, k = i % 72;
        float v = 0.f;
        if (k < 15) v = cw0[n * 47 + k];
        else if (k >= 32 && k < 64) v = cw0[n * 47 + k - 17];
        w[OC0 + i] = f2bf(v);
    }
    for (int i = tid; i < 64 * 72; i += 1024) { int n = i / 72, k = i % 72; w[OC1 + i] = f2bf(k < 64 ? cw1[n * 64 + k] : 0.f); }
    for (int i = tid; i < 64 * 72; i += 1024) { int n = i / 72, k = i % 72; w[OC2 + i] = f2bf(k < 64 ? cw2[n * 64 + k] : 0.f); }
    for (int i = tid; i < 16 * 72; i += 1024) { int n = i / 72, k = i % 72; w[OW2 + i] = f2bf(k < 64 ? sw2[n * 64 + k] : 0.f); }
    for (int i = tid; i < 16 * 72; i += 1024) { int n = i / 72, k = i % 72; w[OC3 + i] = f2bf((n < 3 && k < 64) ? cw3[n * 64 + k] : 0.f); }
    float* gB = reinterpret_cast<float*>(w + OBF);
    if (tid < 64) {
        gB[tid]       = sb0[tid];
        gB[64 + tid]  = sb1[tid];
        gB[144 + tid] = cb0[tid];
        gB[208 + tid] = cb1[tid];
        gB[272 + tid] = cb2[tid];
    }
    if (tid < 16) {
        gB[128 + tid] = sb2[tid];
        gB[336 + tid] = (tid < 3) ? cb3[tid] : 0.f;
    }
}

// One GEMM layer: act[M,K] @ W[N,K]^T + bias, optional relu, bf16 out to LDS.
// W/bias may point to LDS or global (verbatim math from R0/R6).
template<int KS, int NT, bool RELU>
__device__ __forceinline__ void mlp_layer(
    const unsigned short* a0, int s0,
    const unsigned short* a1, int s1,
    const unsigned short* __restrict__ W, int ws,
    const float* __restrict__ bias,
    unsigned short* outp, int os,
    int wave, int lane)
{
    const int lr = lane & 15, lg = lane >> 4;
    bf16x8 bfr[NT][KS];
#pragma unroll
    for (int nt = 0; nt < NT; ++nt)
#pragma unroll
        for (int ks = 0; ks < KS; ++ks)
            bfr[nt][ks] = *reinterpret_cast<const bf16x8*>(W + (nt * 16 + lr) * ws + ks * 32 + lg * 8);

#pragma unroll
    for (int mt = 0; mt < 2; ++mt) {
        const int R = wave * 32 + mt * 16;
        bf16x8 afr[KS];
        afr[0] = *reinterpret_cast<const bf16x8*>(a0 + (R + lr) * s0 + lg * 8);
        if constexpr (KS > 1)
            afr[1] = *reinterpret_cast<const bf16x8*>(a1 + (R + lr) * s1 + lg * 8);

        f32x4 acc[NT] = {};
#pragma unroll
        for (int nt = 0; nt < NT; ++nt)
#pragma unroll
            for (int ks = 0; ks < KS; ++ks)
                acc[nt] = __builtin_amdgcn_mfma_f32_16x16x32_bf16(afr[ks], bfr[nt][ks], acc[nt], 0, 0, 0);

#pragma unroll
        for (int nt = 0; nt < NT; ++nt) {
            const float b = bias[nt * 16 + lr];
#pragma unroll
            for (int r = 0; r < 4; ++r) {
                float v = acc[nt][r] + b;
                if (RELU) v = fmaxf(v, 0.f);
                outp[(R + lg * 4 + r) * os + nt * 16 + lr] = f2bf(v);
            }
        }
    }
}

// ---------------------------------------------------------------------------
// Main fused kernel: fp8 grid + packed weights, both in ws. LDS = act only.
__global__ void __launch_bounds__(NTHR, 8) nerf_fused_v8(
    const float* __restrict__ x, const float* __restrict__ dvec,
    const int*   __restrict__ nidx,
    const unsigned short* __restrict__ gfp8,   // fp8 grid pairs
    const unsigned short* __restrict__ wz,     // packed weights base
    const float* __restrict__ latent,
    float* __restrict__ out, int B)
{
    __shared__ __align__(16) unsigned short sAct[MPB * 72];

    const int tid = threadIdx.x;
    const float* __restrict__ gB = reinterpret_cast<const float*>(wz + OBF);

    // ---------------- Phase 1: hash encode (2 thr/pt, R6-verbatim) ----------------
    const int p  = tid & (MPB - 1);
    const int hv = tid >> 8;                 // wave-uniform level-half selector
    const long long P = (long long)blockIdx.x * MPB + p;

    {
        const float x0 = x[3 * P + 0], x1 = x[3 * P + 1], x2 = x[3 * P + 2];
#pragma unroll 2
        for (int lp = 0; lp < 4; ++lp) {
            unsigned idx[2][8];
            float wxa[2][2], wya[2][2], wza[2][2];
#pragma unroll
            for (int s = 0; s < 2; ++s) {
                const int l = hv * 8 + lp * 2 + s;
                const float res = RES_TAB[l];
                const float px = x0 * res, py = x1 * res, pz = x2 * res;
                const float fx = floorf(px), fy = floorf(py), fz = floorf(pz);
                const float wx = px - fx, wy = py - fy, wz2 = pz - fz;
                const unsigned ix = (unsigned)fx, iy = (unsigned)fy, iz = (unsigned)fz;
                const unsigned hx0 = ix, hx1 = ix + 1u;
                const unsigned hy0 = iy * 2654435761u, hy1 = (iy + 1u) * 2654435761u;
                const unsigned hz0 = iz * 805459861u,  hz1 = (iz + 1u) * 805459861u;
                const unsigned base = (unsigned)l * (unsigned)TBL;
#pragma unroll
                for (int c = 0; c < 8; ++c) {
                    const unsigned h = ((c & 1) ? hx1 : hx0) ^ (((c >> 1) & 1) ? hy1 : hy0)
                                     ^ (((c >> 2) & 1) ? hz1 : hz0);
                    idx[s][c] = base + (h & TMASK);
                }
                wxa[s][0] = 1.f - wx; wxa[s][1] = wx;
                wya[s][0] = 1.f - wy; wya[s][1] = wy;
                wza[s][0] = 1.f - wz2; wza[s][1] = wz2;
            }
            // issue all 16 gathers before consuming
            unsigned short u[2][8];
#pragma unroll
            for (int s = 0; s < 2; ++s)
#pragma unroll
                for (int c = 0; c < 8; ++c)
                    u[s][c] = gfp8[idx[s][c]];
#pragma unroll
            for (int s = 0; s < 2; ++s) {
                float f0 = 0.f, f1 = 0.f;
#pragma unroll
                for (int c = 0; c < 8; ++c) {
                    const float wc = wxa[s][c & 1] * wya[s][(c >> 1) & 1] * wza[s][(c >> 2) & 1];
                    const unsigned uu = u[s][c];
                    f0 = fmaf(fp8_dec(uu & 0xffu), wc, f0);
                    f1 = fmaf(fp8_dec((uu >> 8) & 0xffu), wc, f1);
                }
                const int l = hv * 8 + lp * 2 + s;
                *reinterpret_cast<unsigned*>(&sAct[p * 72 + 2 * l]) =
                    pack2(f0 * FP8_INV_SCALE, f1 * FP8_INV_SCALE);
            }
        }
    }

    // sh16 (hv=0) or latent (hv=1) into 8 registers.
    unsigned creg0, creg1, creg2, creg3, creg4, creg5, creg6, creg7;
    if (hv == 0) {
        // note: (d+1)*0.5*2-1 == d exactly
        const float X = dvec[3 * P + 0], Y = dvec[3 * P + 1], Z = dvec[3 * P + 2];
        const float x2 = X * X, y2 = Y * Y, z2 = Z * Z, xy = X * Y, yz = Y * Z, xz = X * Z;
        const float s0 = 0.28209479177387814f;
        const float s1 = -0.48860251190291987f * Y;
        const float s2 = 0.48860251190291987f * Z;
        const float s3 = -0.48860251190291987f * X;
        const float s4 = 1.0925484305920792f * xy;
        const float s5 = -1.0925484305920792f * yz;
        const float s6 = 0.94617469575756f * z2 - 0.31539156525252f;
        const float s7 = -1.0925484305920792f * xz;
        const float s8 = 0.5462742152960396f * (x2 - y2);
        const float s9 = 0.5900435899266435f * Y * (-3.f * x2 + y2);
        const float s10 = 2.890611442640554f * xy * Z;
        const float s11 = 0.4570457994644657f * Y * (1.f - 5.f * z2);
        const float s12 = 0.3731763325901154f * Z * (5.f * z2 - 3.f);
        const float s13 = 0.4570457994644657f * X * (1.f - 5.f * z2);
        const float s14 = 1.445305721320277f * Z * (x2 - y2);
        const float s15 = 0.5900435899266435f * X * (-x2 + 3.f * y2);
        creg0 = pack2(s0, s1);   creg1 = pack2(s2, s3);
        creg2 = pack2(s4, s5);   creg3 = pack2(s6, s7);
        creg4 = pack2(s8, s9);   creg5 = pack2(s10, s11);
        creg6 = pack2(s12, s13); creg7 = pack2(s14, s15);
    } else {
        const int id = nidx[P];
        const float4* lp = reinterpret_cast<const float4*>(latent + 16 * id);
        const float4 a = lp[0], b = lp[1], c = lp[2], d4 = lp[3];
        creg0 = pack2(a.x, a.y); creg1 = pack2(a.z, a.w);
        creg2 = pack2(b.x, b.y); creg3 = pack2(b.z, b.w);
        creg4 = pack2(c.x, c.y); creg5 = pack2(c.z, c.w);
        creg6 = pack2(d4.x, d4.y); creg7 = pack2(d4.z, d4.w);
    }

    __syncthreads();   // barrier 1: hash done

    // ---------------- Phase 2: MLPs (8 waves x 32-row tiles) ----------------
    const int lane = tid & 63;
    const int wave = tid >> 6;       // 0..7

    // sigma net
    mlp_layer<1, 4, true>(sAct, 72, nullptr, 0,    wz + OW0, 40, gB + 0,  sAct, 72, wave, lane);
    mlp_layer<2, 4, true>(sAct, 72, sAct + 32, 72, wz + OW1, 72, gB + 64, sAct, 72, wave, lane);

    // s = a2 @ sw2^T + sb2 (no relu). col0 -> sigma, cols 1..15 -> geo (cols 0..14),
    // cols 15..31 zeroed (cin padding).
    {
        const int lr = lane & 15, lg = lane >> 4;
        const bf16x8 b0 = *reinterpret_cast<const bf16x8*>(wz + OW2 + lr * 72 + lg * 8);
        const bf16x8 b1 = *reinterpret_cast<const bf16x8*>(wz + OW2 + lr * 72 + 32 + lg * 8);
        const float bb = gB[128 + lr];
#pragma unroll
        for (int mt = 0; mt < 2; ++mt) {
            const int R = wave * 32 + mt * 16;
            const bf16x8 a0 = *reinterpret_cast<const bf16x8*>(sAct + (R + lr) * 72 + lg * 8);
            const bf16x8 a1 = *reinterpret_cast<const bf16x8*>(sAct + (R + lr) * 72 + 32 + lg * 8);
            f32x4 acc = {};
            acc = __builtin_amdgcn_mfma_f32_16x16x32_bf16(a0, b0, acc, 0, 0, 0);
            acc = __builtin_amdgcn_mfma_f32_16x16x32_bf16(a1, b1, acc, 0, 0, 0);
#pragma unroll
            for (int r = 0; r < 4; ++r) {
                const float v = acc[r] + bb;
                const int row = R + lg * 4 + r;
                if (lr == 0) {
                    out[(long long)blockIdx.x * MPB + row] = v;   // sigma (f32)
                    sAct[row * 72 + 31] = 0;
                } else {
                    sAct[row * 72 + lr - 1] = f2bf(v);            // geo
                }
                sAct[row * 72 + 15 + lr] = 0;                     // zero cols 15..30 (+31 above)
            }
        }
    }

    __syncthreads();   // barrier 2: all sigma-net LDS reads complete

    // insert sh (cols 32..47) / latent (cols 48..63) from registers
    {
        unsigned* c2 = reinterpret_cast<unsigned*>(&sAct[p * 72 + 32 + hv * 16]);
        c2[0] = creg0; c2[1] = creg1; c2[2] = creg2; c2[3] = creg3;
        c2[4] = creg4; c2[5] = creg5; c2[6] = creg6; c2[7] = creg7;
    }

    __syncthreads();   // barrier 3: cin complete

    // color net (in-place on sAct, cols 0..63)
    mlp_layer<2, 4, true>(sAct, 72, sAct + 32, 72, wz + OC0, 72, gB + 144, sAct, 72, wave, lane);
    mlp_layer<2, 4, true>(sAct, 72, sAct + 32, 72, wz + OC1, 72, gB + 208, sAct, 72, wave, lane);
    mlp_layer<2, 4, true>(sAct, 72, sAct + 32, 72, wz + OC2, 72, gB + 272, sAct, 72, wave, lane);

    // final: 64 -> 3 (padded to 16), sigmoid
    {
        const int lr = lane & 15, lg = lane >> 4;
        const bf16x8 b0 = *reinterpret_cast<const bf16x8*>(wz + OC3 + lr * 72 + lg * 8);
        const bf16x8 b1 = *reinterpret_cast<const bf16x8*>(wz + OC3 + lr * 72 + 32 + lg * 8);
        const float bb = gB[336 + lr];
#pragma unroll
        for (int mt = 0; mt < 2; ++mt) {
            const int R = wave * 32 + mt * 16;
            const bf16x8 a0 = *reinterpret_cast<const bf16x8*>(sAct + (R + lr) * 72 + lg * 8);
            const bf16x8 a1 = *reinterpret_cast<const bf16x8*>(sAct + (R + lr) * 72 + 32 + lg * 8);
            f32x4 acc = {};
            acc = __builtin_amdgcn_mfma_f32_16x16x32_bf16(a0, b0, acc, 0, 0, 0);
            acc = __builtin_amdgcn_mfma_f32_16x16x32_bf16(a1, b1, acc, 0, 0, 0);
            if (lr < 3) {
#pragma unroll
                for (int r = 0; r < 4; ++r) {
                    const float v = acc[r] + bb;
                    const long long row = (long long)blockIdx.x * MPB + R + lg * 4 + r;
                    out[(long long)B + row * 3 + lr] = 1.f / (1.f + __expf(-v));
                }
            }
        }
    }
}

// ---------------------------------------------------------------------------
// Fallback: R6's full-LDS f32-grid fused kernel (512 pts, 1024 thr), proven.
__global__ void __launch_bounds__(1024, 4) nerf_fused_f32(
    const float* __restrict__ x, const float* __restrict__ dvec,
    const int*   __restrict__ nidx, const float* __restrict__ grid,
    const float* __restrict__ latent,
    const float* __restrict__ sw0, const float* __restrict__ sb0,
    const float* __restrict__ sw1, const float* __restrict__ sb1,
    const float* __restrict__ sw2, const float* __restrict__ sb2,
    const float* __restrict__ cw0, const float* __restrict__ cb0,
    const float* __restrict__ cw1, const float* __restrict__ cb1,
    const float* __restrict__ cw2, const float* __restrict__ cb2,
    const float* __restrict__ cw3, const float* __restrict__ cb3,
    float* __restrict__ out, int B)
{
    __shared__ __align__(16) unsigned short sW0[64 * 40];
    __shared__ __align__(16) unsigned short sW1[64 * 72];
    __shared__ __align__(16) unsigned short sW2[16 * 72];
    __shared__ __align__(16) unsigned short sC0[64 * 72];
    __shared__ __align__(16) unsigned short sC1[64 * 72];
    __shared__ __align__(16) unsigned short sC2[64 * 72];
    __shared__ __align__(16) unsigned short sC3[16 * 72];
    __shared__ float sB[352];
    __shared__ __align__(16) unsigned short sAct[512 * 72];

    const int tid = threadIdx.x;

    for (int i = tid; i < 64 * 40; i += 1024) { int n = i / 40, k = i % 40; sW0[i] = f2bf(k < 32 ? sw0[n * 32 + k] : 0.f); }
    for (int i = tid; i < 64 * 72; i += 1024) { int n = i / 72, k = i % 72; sW1[i] = f2bf(k < 64 ? sw1[n * 64 + k] : 0.f); }
    for (int i = tid; i < 16 * 72; i += 1024) { int n = i / 72, k = i % 72; sW2[i] = f2bf(k < 64 ? sw2[n * 64 + k] : 0.f); }
    for (int i = tid; i < 64 * 72; i += 1024) {
        int n = i / 72, k = i % 72;
        float v = 0.f;
        if (k < 15) v = cw0[n * 47 + k];
        else if (k >= 32 && k < 64) v = cw0[n * 47 + k - 17];
        sC0[i] = f2bf(v);
    }
    for (int i = tid; i < 64 * 72; i += 1024) { int n = i / 72, k = i % 72; sC1[i] = f2bf(k < 64 ? cw1[n * 64 + k] : 0.f); }
    for (int i = tid; i < 64 * 72; i += 1024) { int n = i / 72, k = i % 72; sC2[i] = f2bf(k < 64 ? cw2[n * 64 + k] : 0.f); }
    for (int i = tid; i < 16 * 72; i += 1024) { int n = i / 72, k = i % 72; sC3[i] = f2bf((n < 3 && k < 64) ? cw3[n * 64 + k] : 0.f); }
    if (tid < 64) {
        sB[tid]       = sb0[tid];
        sB[64 + tid]  = sb1[tid];
        sB[144 + tid] = cb0[tid];
        sB[208 + tid] = cb1[tid];
        sB[272 + tid] = cb2[tid];
    }
    if (tid < 16) {
        sB[128 + tid] = sb2[tid];
        sB[336 + tid] = (tid < 3) ? cb3[tid] : 0.f;
    }

    const int p  = tid & 511;
    const int hv = tid >> 9;
    const long long P = (long long)blockIdx.x * 512 + p;

    {
        const float x0 = x[3 * P + 0], x1 = x[3 * P + 1], x2 = x[3 * P + 2];
        const float2* __restrict__ gtab = reinterpret_cast<const float2*>(grid);
#pragma unroll 2
        for (int ll = 0; ll < 8; ++ll) {
            const int l = hv * 8 + ll;
            const float res = RES_TAB[l];
            const float px = x0 * res, py = x1 * res, pz = x2 * res;
            const float fx = floorf(px), fy = floorf(py), fz = floorf(pz);
            const float wx = px - fx, wy = py - fy, wz = pz - fz;
            const unsigned ix = (unsigned)fx, iy = (unsigned)fy, iz = (unsigned)fz;
            const unsigned hx[2] = { ix, ix + 1u };
            const unsigned hy[2] = { iy * 2654435761u, (iy + 1u) * 2654435761u };
            const unsigned hz[2] = { iz * 805459861u, (iz + 1u) * 805459861u };
            const float2* tl = gtab + (size_t)l * TBL;
            float2 g[8];
#pragma unroll
            for (int c = 0; c < 8; ++c) {
                const unsigned h = hx[c & 1] ^ hy[(c >> 1) & 1] ^ hz[(c >> 2) & 1];
                g[c] = tl[h & TMASK];
            }
            const float wxa[2] = { 1.f - wx, wx }, wya[2] = { 1.f - wy, wy }, wza[2] = { 1.f - wz, wz };
            float f0 = 0.f, f1 = 0.f;
#pragma unroll
            for (int c = 0; c < 8; ++c) {
                const float wc = wxa[c & 1] * wya[(c >> 1) & 1] * wza[(c >> 2) & 1];
                f0 = fmaf(g[c].x, wc, f0);
                f1 = fmaf(g[c].y, wc, f1);
            }
            *reinterpret_cast<unsigned*>(&sAct[p * 72 + 2 * l]) = pack2(f0, f1);
        }
    }

    unsigned creg0, creg1, creg2, creg3, creg4, creg5, creg6, creg7;
    if (hv == 0) {
        const float X = dvec[3 * P + 0], Y = dvec[3 * P + 1], Z = dvec[3 * P + 2];
        const float x2 = X * X, y2 = Y * Y, z2 = Z * Z, xy = X * Y, yz = Y * Z, xz = X * Z;
        const float s0 = 0.28209479177387814f;
        const float s1 = -0.48860251190291987f * Y;
        const float s2 = 0.48860251190291987f * Z;
        const float s3 = -0.48860251190291987f * X;
        const float s4 = 1.0925484305920792f * xy;
        const float s5 = -1.0925484305920792f * yz;
        const float s6 = 0.94617469575756f * z2 - 0.31539156525252f;
        const float s7 = -1.0925484305920792f * xz;
        const float s8 = 0.5462742152960396f * (x2 - y2);
        const float s9 = 0.5900435899266435f * Y * (-3.f * x2 + y2);
        const float s10 = 2.890611442640554f * xy * Z;
        const float s11 = 0.4570457994644657f * Y * (1.f - 5.f * z2);
        const float s12 = 0.3731763325901154f * Z * (5.f * z2 - 3.f);
        const float s13 = 0.4570457994644657f * X * (1.f - 5.f * z2);
        const float s14 = 1.445305721320277f * Z * (x2 - y2);
        const float s15 = 0.5900435899266435f * X * (-x2 + 3.f * y2);
        creg0 = pack2(s0, s1);   creg1 = pack2(s2, s3);
        creg2 = pack2(s4, s5);   creg3 = pack2(s6, s7);
        creg4 = pack2(s8, s9);   creg5 = pack2(s10, s11);
        creg6 = pack2(s12, s13); creg7 = pack2(s14, s15);
    } else {
        const int id = nidx[P];
        const float4* lp = reinterpret_cast<const float4*>(latent + 16 * id);
        const float4 a = lp[0], b = lp[1], c = lp[2], d4 = lp[3];
        creg0 = pack2(a.x, a.y); creg1 = pack2(a.z, a.w);
        creg2 = pack2(b.x, b.y); creg3 = pack2(b.z, b.w);
        creg4 = pack2(c.x, c.y); creg5 = pack2(c.z, c.w);
        creg6 = pack2(d4.x, d4.y); creg7 = pack2(d4.z, d4.w);
    }

    __syncthreads();

    const int lane = tid & 63;
    const int wave = tid >> 6;

    mlp_layer<1, 4, true>(sAct, 72, nullptr, 0,    sW0, 40, sB + 0,  sAct, 72, wave, lane);
    mlp_layer<2, 4, true>(sAct, 72, sAct + 32, 72, sW1, 72, sB + 64, sAct, 72, wave, lane);

    {
        const int lr = lane & 15, lg = lane >> 4;
        const bf16x8 b0 = *reinterpret_cast<const bf16x8*>(sW2 + lr * 72 + lg * 8);
        const bf16x8 b1 = *reinterpret_cast<const bf16x8*>(sW2 + lr * 72 + 32 + lg * 8);
        const float bb = sB[128 + lr];
#pragma unroll
        for (int mt = 0; mt < 2; ++mt) {
            const int R = wave * 32 + mt * 16;
            const bf16x8 a0 = *reinterpret_cast<const bf16x8*>(sAct + (R + lr) * 72 + lg * 8);
            const bf16x8 a1 = *reinterpret_cast<const bf16x8*>(sAct + (R + lr) * 72 + 32 + lg * 8);
            f32x4 acc = {};
            acc = __builtin_amdgcn_mfma_f32_16x16x32_bf16(a0, b0, acc, 0, 0, 0);
            acc = __builtin_amdgcn_mfma_f32_16x16x32_bf16(a1, b1, acc, 0, 0, 0);
#pragma unroll
            for (int r = 0; r < 4; ++r) {
                const float v = acc[r] + bb;
                const int row = R + lg * 4 + r;
                if (lr == 0) {
                    out[(long long)blockIdx.x * 512 + row] = v;
                    sAct[row * 72 + 31] = 0;
                } else {
                    sAct[row * 72 + lr - 1] = f2bf(v);
                }
                sAct[row * 72 + 15 + lr] = 0;
            }
        }
    }

    __syncthreads();

    {
        unsigned* c2 = reinterpret_cast<unsigned*>(&sAct[p * 72 + 32 + hv * 16]);
        c2[0] = creg0; c2[1] = creg1; c2[2] = creg2; c2[3] = creg3;
        c2[4] = creg4; c2[5] = creg5; c2[6] = creg6; c2[7] = creg7;
    }

    __syncthreads();

    mlp_layer<2, 4, true>(sAct, 72, sAct + 32, 72, sC0, 72, sB + 144, sAct, 72, wave, lane);
    mlp_layer<2, 4, true>(sAct, 72, sAct + 32, 72, sC1, 72, sB + 208, sAct, 72, wave, lane);
    mlp_layer<2, 4, true>(sAct, 72, sAct + 32, 72, sC2, 72, sB + 272, sAct, 72, wave, lane);

    {
        const int lr = lane & 15, lg = lane >> 4;
        const bf16x8 b0 = *reinterpret_cast<const bf16x8*>(sC3 + lr * 72 + lg * 8);
        const bf16x8 b1 = *reinterpret_cast<const bf16x8*>(sC3 + lr * 72 + 32 + lg * 8);
        const float bb = sB[336 + lr];
#pragma unroll
        for (int mt = 0; mt < 2; ++mt) {
            const int R = wave * 32 + mt * 16;
            const bf16x8 a0 = *reinterpret_cast<const bf16x8*>(sAct + (R + lr) * 72 + lg * 8);
            const bf16x8 a1 = *reinterpret_cast<const bf16x8*>(sAct + (R + lr) * 72 + 32 + lg * 8);
            f32x4 acc = {};
            acc = __builtin_amdgcn_mfma_f32_16x16x32_bf16(a0, b0, acc, 0, 0, 0);
            acc = __builtin_amdgcn_mfma_f32_16x16x32_bf16(a1, b1, acc, 0, 0, 0);
            if (lr < 3) {
#pragma unroll
                for (int r = 0; r < 4; ++r) {
                    const float v = acc[r] + bb;
                    const long long row = (long long)blockIdx.x * 512 + R + lg * 4 + r;
                    out[(long long)B + row * 3 + lr] = 1.f / (1.f + __expf(-v));
                }
            }
        }
    }
}

// ---------------------------------------------------------------------------
extern "C" void kernel_launch(void* const* d_in, const int* in_sizes, int n_in,
                              void* d_out, int out_size, void* d_ws, size_t ws_size,
                              hipStream_t stream) {
    const float* x    = (const float*)d_in[0];
    const float* dv   = (const float*)d_in[1];
    const int*   n    = (const int*)d_in[2];
    const float* grid = (const float*)d_in[3];
    const float* lat  = (const float*)d_in[4];
    const float* sw0  = (const float*)d_in[5];
    const float* sb0  = (const float*)d_in[6];
    const float* sw1  = (const float*)d_in[7];
    const float* sb1  = (const float*)d_in[8];
    const float* sw2  = (const float*)d_in[9];
    const float* sb2  = (const float*)d_in[10];
    const float* cw0  = (const float*)d_in[11];
    const float* cb0  = (const float*)d_in[12];
    const float* cw1  = (const float*)d_in[13];
    const float* cb1  = (const float*)d_in[14];
    const float* cw2  = (const float*)d_in[15];
    const float* cb2  = (const float*)d_in[16];
    const float* cw3  = (const float*)d_in[17];
    const float* cb3  = (const float*)d_in[18];

    const int B = in_sizes[2];           // 1048576

    if (ws_size >= WS_NEED && (B % MPB) == 0) {
        unsigned short* wsS = (unsigned short*)d_ws;                 // fp8 grid
        unsigned short* wz  = (unsigned short*)((char*)d_ws + GRID_BYTES); // weights
        grid_to_fp8<<<dim3((GRID_SHORTS + 1023) / 1024), dim3(1024), 0, stream>>>(
            reinterpret_cast<const float2*>(grid), wsS, GRID_SHORTS);
        pack_weights<<<dim3(1), dim3(1024), 0, stream>>>(
            wz, sw0, sb0, sw1, sb1, sw2, sb2,
            cw0, cb0, cw1, cb1, cw2, cb2, cw3, cb3);
        nerf_fused_v8<<<dim3(B / MPB), dim3(NTHR), 0, stream>>>(
            x, dv, n, wsS, wz, lat, (float*)d_out, B);
    } else {
        nerf_fused_f32<<<dim3(B / 512), dim3(1024), 0, stream>>>(
            x, dv, n, grid, lat,
            sw0, sb0, sw1, sb1, sw2, sb2,
            cw0, cb0, cw1, cb1, cw2, cb2, cw3, cb3,
            (float*)d_out, B);
    }
}

// Round 10
// 652.136 us; speedup vs baseline: 1.1774x; 1.1774x over previous
//
#include <hip/hip_runtime.h>
#include <hip/hip_bf16.h>
#include <hip/hip_fp8.h>

// v10 = v6 (passed, 621us) with ONE thread-local change: the fp8 hash-gather
// loop batches 4 levels (32 outstanding loads/thread) instead of 2 (16).
// Same level set, same per-level math, same sAct writes -> bit-identical
// output to v6. No sync-structure changes (the R2/R3/v9 restructured family
// showed a codegen-dependent corruption; abandoned).
// Fallback f32-grid path (R4-verbatim) if ws_size < 16MB.

#define TBL   524288      // T = 1<<19
#define TMASK (TBL - 1)
#define MPB   512         // points per block
#define NTHR  1024

#define FP8_SCALE     1048576.0f          // 2^20
#define FP8_INV_SCALE 9.5367431640625e-7f // 2^-20

typedef __bf16 bf16x8 __attribute__((ext_vector_type(8)));
typedef float  f32x4  __attribute__((ext_vector_type(4)));

// floor(16 * 1.3819^l) for l = 0..15 (computed in double; all >=0.04 from integer)
__device__ const float RES_TAB[16] = {
    16.f, 22.f, 30.f, 42.f, 58.f, 80.f, 111.f, 153.f,
    212.f, 294.f, 406.f, 561.f, 775.f, 1072.f, 1481.f, 2047.f
};

__device__ __forceinline__ unsigned short f2bf(float f) {
    __hip_bfloat16 h = __float2bfloat16(f);
    unsigned short u;
    __builtin_memcpy(&u, &h, 2);
    return u;
}
__device__ __forceinline__ unsigned pack2(float a, float b) {
    return (unsigned)f2bf(a) | ((unsigned)f2bf(b) << 16);
}

// ---- fp8 e4m3 (OCP) helpers ----
__device__ __forceinline__ float fp8_dec(unsigned b) {
#if defined(__has_builtin) && __has_builtin(__builtin_amdgcn_cvt_f32_fp8)
    return __builtin_amdgcn_cvt_f32_fp8((int)b, 0);
#else
    const unsigned e = (b >> 3) & 0xF, m = b & 7;
    float v = e ? ldexpf((float)(8 + m), (int)e - 10) : ldexpf((float)m, -9);
    return (b & 0x80) ? -v : v;
#endif
}
__device__ __forceinline__ unsigned short fp8_pair(float a, float b) {
#if defined(__has_builtin) && __has_builtin(__builtin_amdgcn_cvt_pk_fp8_f32)
    return (unsigned short)(__builtin_amdgcn_cvt_pk_fp8_f32(a, b, 0, false) & 0xffff);
#else
    __hip_fp8_e4m3 qa(a), qb(b);
    return (unsigned short)((unsigned)qa.__x | ((unsigned)qb.__x << 8));
#endif
}

// ---------------------------------------------------------------------------
// grid (f32 pairs) -> packed fp8 pairs (scaled by 2^20) in ws. 16*TBL entries.
__global__ void __launch_bounds__(1024) grid_to_fp8(
    const float2* __restrict__ g, unsigned short* __restrict__ o, int n)
{
    const int i = blockIdx.x * 1024 + threadIdx.x;
    if (i < n) {
        const float2 v = g[i];
        o[i] = fp8_pair(v.x * FP8_SCALE, v.y * FP8_SCALE);
    }
}

// One GEMM layer: act[M,K] @ W[N,K]^T + bias, optional relu, bf16 out to LDS.
// (verbatim from R0/R4)
template<int KS, int NT, bool RELU>
__device__ __forceinline__ void mlp_layer(
    const unsigned short* a0, int s0,
    const unsigned short* a1, int s1,
    const unsigned short* __restrict__ W, int ws,
    const float* __restrict__ bias,
    unsigned short* outp, int os,
    int wave, int lane)
{
    const int lr = lane & 15, lg = lane >> 4;
    bf16x8 bfr[NT][KS];
#pragma unroll
    for (int nt = 0; nt < NT; ++nt)
#pragma unroll
        for (int ks = 0; ks < KS; ++ks)
            bfr[nt][ks] = *reinterpret_cast<const bf16x8*>(W + (nt * 16 + lr) * ws + ks * 32 + lg * 8);

#pragma unroll
    for (int mt = 0; mt < 2; ++mt) {
        const int R = wave * 32 + mt * 16;
        bf16x8 afr[KS];
        afr[0] = *reinterpret_cast<const bf16x8*>(a0 + (R + lr) * s0 + lg * 8);
        if constexpr (KS > 1)
            afr[1] = *reinterpret_cast<const bf16x8*>(a1 + (R + lr) * s1 + lg * 8);

        f32x4 acc[NT] = {};
#pragma unroll
        for (int nt = 0; nt < NT; ++nt)
#pragma unroll
            for (int ks = 0; ks < KS; ++ks)
                acc[nt] = __builtin_amdgcn_mfma_f32_16x16x32_bf16(afr[ks], bfr[nt][ks], acc[nt], 0, 0, 0);

#pragma unroll
        for (int nt = 0; nt < NT; ++nt) {
            const float b = bias[nt * 16 + lr];
#pragma unroll
            for (int r = 0; r < 4; ++r) {
                float v = acc[nt][r] + b;
                if (RELU) v = fmaxf(v, 0.f);
                outp[(R + lg * 4 + r) * os + nt * 16 + lr] = f2bf(v);
            }
        }
    }
}

// GM=1: grid points at packed fp8 pairs (ushort, TBL per level), 4-level batched.
// GM=0: grid points at f32 pairs (float2, TBL per level) — R4 verbatim path.
template<int GM>
__global__ void __launch_bounds__(NTHR, 4) nerf_fused(
    const float* __restrict__ x, const float* __restrict__ dvec,
    const int*   __restrict__ nidx, const void* __restrict__ grid,
    const float* __restrict__ latent,
    const float* __restrict__ sw0, const float* __restrict__ sb0,
    const float* __restrict__ sw1, const float* __restrict__ sb1,
    const float* __restrict__ sw2, const float* __restrict__ sb2,
    const float* __restrict__ cw0, const float* __restrict__ cb0,
    const float* __restrict__ cw1, const float* __restrict__ cb1,
    const float* __restrict__ cw2, const float* __restrict__ cb2,
    const float* __restrict__ cw3, const float* __restrict__ cb3,
    float* __restrict__ out, int B)
{
    // Weight LDS: [n][k] bf16, strides padded (40 for K=32, 72 for K=64).
    __shared__ __align__(16) unsigned short sW0[64 * 40];
    __shared__ __align__(16) unsigned short sW1[64 * 72];
    __shared__ __align__(16) unsigned short sW2[16 * 72];
    __shared__ __align__(16) unsigned short sC0[64 * 72];
    __shared__ __align__(16) unsigned short sC1[64 * 72];
    __shared__ __align__(16) unsigned short sC2[64 * 72];
    __shared__ __align__(16) unsigned short sC3[16 * 72];
    __shared__ float sB[352]; // b0@0, b1@64, b2@128(16), cb0@144, cb1@208, cb2@272, cb3@336(16)
    __shared__ __align__(16) unsigned short sAct[MPB * 72];   // activations, in-place across layers

    const int tid = threadIdx.x;

    // ---------------- Phase 1: stage weights ----------------
    for (int i = tid; i < 64 * 40; i += NTHR) { int n = i / 40, k = i % 40; sW0[i] = f2bf(k < 32 ? sw0[n * 32 + k] : 0.f); }
    for (int i = tid; i < 64 * 72; i += NTHR) { int n = i / 72, k = i % 72; sW1[i] = f2bf(k < 64 ? sw1[n * 64 + k] : 0.f); }
    for (int i = tid; i < 16 * 72; i += NTHR) { int n = i / 72, k = i % 72; sW2[i] = f2bf(k < 64 ? sw2[n * 64 + k] : 0.f); }
    // cw0 is [64][47] over cin order [geo(0..14) | sh(15..30) | lat(31..46)].
    // Our cin layout: k' 0..14 = geo, k' 15..31 = zero, k' 32..47 = sh, k' 48..63 = lat.
    for (int i = tid; i < 64 * 72; i += NTHR) {
        int n = i / 72, k = i % 72;
        float v = 0.f;
        if (k < 15) v = cw0[n * 47 + k];
        else if (k >= 32 && k < 64) v = cw0[n * 47 + k - 17];
        sC0[i] = f2bf(v);
    }
    for (int i = tid; i < 64 * 72; i += NTHR) { int n = i / 72, k = i % 72; sC1[i] = f2bf(k < 64 ? cw1[n * 64 + k] : 0.f); }
    for (int i = tid; i < 64 * 72; i += NTHR) { int n = i / 72, k = i % 72; sC2[i] = f2bf(k < 64 ? cw2[n * 64 + k] : 0.f); }
    for (int i = tid; i < 16 * 72; i += NTHR) { int n = i / 72, k = i % 72; sC3[i] = f2bf((n < 3 && k < 64) ? cw3[n * 64 + k] : 0.f); }
    if (tid < 64) {
        sB[tid]       = sb0[tid];
        sB[64 + tid]  = sb1[tid];
        sB[144 + tid] = cb0[tid];
        sB[208 + tid] = cb1[tid];
        sB[272 + tid] = cb2[tid];
    }
    if (tid < 16) {
        sB[128 + tid] = sb2[tid];
        sB[336 + tid] = (tid < 3) ? cb3[tid] : 0.f;
    }

    // ---------------- Phase 2: hash encode + sh/lat into registers ----------------
    const int p  = tid & (MPB - 1);
    const int hv = tid >> 9;                 // wave-uniform level-half selector
    const long long P = (long long)blockIdx.x * MPB + p;

    if constexpr (GM == 1) {
        const float x0 = x[3 * P + 0], x1 = x[3 * P + 1], x2 = x[3 * P + 2];
        const unsigned short* __restrict__ tf = reinterpret_cast<const unsigned short*>(grid);
        // 2 batches x 4 levels: 32 gathers in flight per batch (v6 had 2x8=16).
        for (int lp = 0; lp < 2; ++lp) {
            unsigned idx[4][8];
            float wxa[4][2], wya[4][2], wza[4][2];
#pragma unroll
            for (int s = 0; s < 4; ++s) {
                const int l = hv * 8 + lp * 4 + s;
                const float res = RES_TAB[l];
                const float px = x0 * res, py = x1 * res, pz = x2 * res;
                const float fx = floorf(px), fy = floorf(py), fz = floorf(pz);
                const float wx = px - fx, wy = py - fy, wz = pz - fz;
                const unsigned ix = (unsigned)fx, iy = (unsigned)fy, iz = (unsigned)fz;
                const unsigned hx0 = ix, hx1 = ix + 1u;
                const unsigned hy0 = iy * 2654435761u, hy1 = (iy + 1u) * 2654435761u;
                const unsigned hz0 = iz * 805459861u,  hz1 = (iz + 1u) * 805459861u;
                const unsigned base = (unsigned)l * (unsigned)TBL;
#pragma unroll
                for (int c = 0; c < 8; ++c) {
                    const unsigned h = ((c & 1) ? hx1 : hx0) ^ (((c >> 1) & 1) ? hy1 : hy0)
                                     ^ (((c >> 2) & 1) ? hz1 : hz0);
                    idx[s][c] = base + (h & TMASK);
                }
                wxa[s][0] = 1.f - wx; wxa[s][1] = wx;
                wya[s][0] = 1.f - wy; wya[s][1] = wy;
                wza[s][0] = 1.f - wz; wza[s][1] = wz;
            }
            // issue all 32 gathers before consuming (2x the in-flight loads of v6)
            unsigned short u[4][8];
#pragma unroll
            for (int s = 0; s < 4; ++s)
#pragma unroll
                for (int c = 0; c < 8; ++c)
                    u[s][c] = tf[idx[s][c]];
#pragma unroll
            for (int s = 0; s < 4; ++s) {
                float f0 = 0.f, f1 = 0.f;
#pragma unroll
                for (int c = 0; c < 8; ++c) {
                    const float wc = wxa[s][c & 1] * wya[s][(c >> 1) & 1] * wza[s][(c >> 2) & 1];
                    const unsigned uu = u[s][c];
                    f0 = fmaf(fp8_dec(uu & 0xffu), wc, f0);
                    f1 = fmaf(fp8_dec((uu >> 8) & 0xffu), wc, f1);
                }
                const int l = hv * 8 + lp * 4 + s;
                *reinterpret_cast<unsigned*>(&sAct[p * 72 + 2 * l]) =
                    pack2(f0 * FP8_INV_SCALE, f1 * FP8_INV_SCALE);
            }
        }
    } else {
        const float x0 = x[3 * P + 0], x1 = x[3 * P + 1], x2 = x[3 * P + 2];
        const float2* __restrict__ gtab = reinterpret_cast<const float2*>(grid);
#pragma unroll 2
        for (int ll = 0; ll < 8; ++ll) {
            const int l = hv * 8 + ll;
            const float res = RES_TAB[l];
            const float px = x0 * res, py = x1 * res, pz = x2 * res;
            const float fx = floorf(px), fy = floorf(py), fz = floorf(pz);
            const float wx = px - fx, wy = py - fy, wz = pz - fz;
            const unsigned ix = (unsigned)fx, iy = (unsigned)fy, iz = (unsigned)fz;
            const unsigned hx[2] = { ix, ix + 1u };
            const unsigned hy[2] = { iy * 2654435761u, (iy + 1u) * 2654435761u };
            const unsigned hz[2] = { iz * 805459861u, (iz + 1u) * 805459861u };
            const float2* tl = gtab + (size_t)l * TBL;
            float2 g[8];
#pragma unroll
            for (int c = 0; c < 8; ++c) {
                const unsigned h = hx[c & 1] ^ hy[(c >> 1) & 1] ^ hz[(c >> 2) & 1];
                g[c] = tl[h & TMASK];
            }
            const float wxa[2] = { 1.f - wx, wx }, wya[2] = { 1.f - wy, wy }, wza[2] = { 1.f - wz, wz };
            float f0 = 0.f, f1 = 0.f;
#pragma unroll
            for (int c = 0; c < 8; ++c) {
                const float wc = wxa[c & 1] * wya[(c >> 1) & 1] * wza[(c >> 2) & 1];
                f0 = fmaf(g[c].x, wc, f0);
                f1 = fmaf(g[c].y, wc, f1);
            }
            *reinterpret_cast<unsigned*>(&sAct[p * 72 + 2 * l]) = pack2(f0, f1);
        }
    }

    // sh16 (hv=0) or latent (hv=1) into 8 registers, statically indexed.
    unsigned creg0, creg1, creg2, creg3, creg4, creg5, creg6, creg7;
    if (hv == 0) {
        // note: (d+1)*0.5*2-1 == d exactly
        const float X = dvec[3 * P + 0], Y = dvec[3 * P + 1], Z = dvec[3 * P + 2];
        const float x2 = X * X, y2 = Y * Y, z2 = Z * Z, xy = X * Y, yz = Y * Z, xz = X * Z;
        const float s0 = 0.28209479177387814f;
        const float s1 = -0.48860251190291987f * Y;
        const float s2 = 0.48860251190291987f * Z;
        const float s3 = -0.48860251190291987f * X;
        const float s4 = 1.0925484305920792f * xy;
        const float s5 = -1.0925484305920792f * yz;
        const float s6 = 0.94617469575756f * z2 - 0.31539156525252f;
        const float s7 = -1.0925484305920792f * xz;
        const float s8 = 0.5462742152960396f * (x2 - y2);
        const float s9 = 0.5900435899266435f * Y * (-3.f * x2 + y2);
        const float s10 = 2.890611442640554f * xy * Z;
        const float s11 = 0.4570457994644657f * Y * (1.f - 5.f * z2);
        const float s12 = 0.3731763325901154f * Z * (5.f * z2 - 3.f);
        const float s13 = 0.4570457994644657f * X * (1.f - 5.f * z2);
        const float s14 = 1.445305721320277f * Z * (x2 - y2);
        const float s15 = 0.5900435899266435f * X * (-x2 + 3.f * y2);
        creg0 = pack2(s0, s1);   creg1 = pack2(s2, s3);
        creg2 = pack2(s4, s5);   creg3 = pack2(s6, s7);
        creg4 = pack2(s8, s9);   creg5 = pack2(s10, s11);
        creg6 = pack2(s12, s13); creg7 = pack2(s14, s15);
    } else {
        const int id = nidx[P];
        const float4* lp = reinterpret_cast<const float4*>(latent + 16 * id);
        const float4 a = lp[0], b = lp[1], c = lp[2], d4 = lp[3];
        creg0 = pack2(a.x, a.y); creg1 = pack2(a.z, a.w);
        creg2 = pack2(b.x, b.y); creg3 = pack2(b.z, b.w);
        creg4 = pack2(c.x, c.y); creg5 = pack2(c.z, c.w);
        creg6 = pack2(d4.x, d4.y); creg7 = pack2(d4.z, d4.w);
    }

    __syncthreads();   // barrier 1: staging + hash done

    // ---------------- Phase 3: MLPs ----------------
    const int lane = tid & 63;
    const int wave = tid >> 6;

    // sigma net
    mlp_layer<1, 4, true>(sAct, 72, nullptr, 0,    sW0, 40, sB + 0,  sAct, 72, wave, lane);
    mlp_layer<2, 4, true>(sAct, 72, sAct + 32, 72, sW1, 72, sB + 64, sAct, 72, wave, lane);

    // s = a2 @ sw2^T + sb2 (no relu). col0 -> sigma, cols 1..15 -> geo (cols 0..14),
    // cols 15..31 zeroed (cin padding).
    {
        const int lr = lane & 15, lg = lane >> 4;
        const bf16x8 b0 = *reinterpret_cast<const bf16x8*>(sW2 + lr * 72 + lg * 8);
        const bf16x8 b1 = *reinterpret_cast<const bf16x8*>(sW2 + lr * 72 + 32 + lg * 8);
        const float bb = sB[128 + lr];
#pragma unroll
        for (int mt = 0; mt < 2; ++mt) {
            const int R = wave * 32 + mt * 16;
            const bf16x8 a0 = *reinterpret_cast<const bf16x8*>(sAct + (R + lr) * 72 + lg * 8);
            const bf16x8 a1 = *reinterpret_cast<const bf16x8*>(sAct + (R + lr) * 72 + 32 + lg * 8);
            f32x4 acc = {};
            acc = __builtin_amdgcn_mfma_f32_16x16x32_bf16(a0, b0, acc, 0, 0, 0);
            acc = __builtin_amdgcn_mfma_f32_16x16x32_bf16(a1, b1, acc, 0, 0, 0);
#pragma unroll
            for (int r = 0; r < 4; ++r) {
                const float v = acc[r] + bb;
                const int row = R + lg * 4 + r;
                if (lr == 0) {
                    out[(long long)blockIdx.x * MPB + row] = v;   // sigma (f32)
                    sAct[row * 72 + 31] = 0;
                } else {
                    sAct[row * 72 + lr - 1] = f2bf(v);            // geo
                }
                sAct[row * 72 + 15 + lr] = 0;                     // zero cols 15..30 (+31 above)
            }
        }
    }

    __syncthreads();   // barrier 2: all sigma-net LDS reads complete

    // insert sh (cols 32..47) / latent (cols 48..63) from registers
    {
        unsigned* c2 = reinterpret_cast<unsigned*>(&sAct[p * 72 + 32 + hv * 16]);
        c2[0] = creg0; c2[1] = creg1; c2[2] = creg2; c2[3] = creg3;
        c2[4] = creg4; c2[5] = creg5; c2[6] = creg6; c2[7] = creg7;
    }

    __syncthreads();   // barrier 3: cin complete

    // color net (in-place on sAct, cols 0..63)
    mlp_layer<2, 4, true>(sAct, 72, sAct + 32, 72, sC0, 72, sB + 144, sAct, 72, wave, lane);
    mlp_layer<2, 4, true>(sAct, 72, sAct + 32, 72, sC1, 72, sB + 208, sAct, 72, wave, lane);
    mlp_layer<2, 4, true>(sAct, 72, sAct + 32, 72, sC2, 72, sB + 272, sAct, 72, wave, lane);

    // final: 64 -> 3 (padded to 16), sigmoid
    {
        const int lr = lane & 15, lg = lane >> 4;
        const bf16x8 b0 = *reinterpret_cast<const bf16x8*>(sC3 + lr * 72 + lg * 8);
        const bf16x8 b1 = *reinterpret_cast<const bf16x8*>(sC3 + lr * 72 + 32 + lg * 8);
        const float bb = sB[336 + lr];
#pragma unroll
        for (int mt = 0; mt < 2; ++mt) {
            const int R = wave * 32 + mt * 16;
            const bf16x8 a0 = *reinterpret_cast<const bf16x8*>(sAct + (R + lr) * 72 + lg * 8);
            const bf16x8 a1 = *reinterpret_cast<const bf16x8*>(sAct + (R + lr) * 72 + 32 + lg * 8);
            f32x4 acc = {};
            acc = __builtin_amdgcn_mfma_f32_16x16x32_bf16(a0, b0, acc, 0, 0, 0);
            acc = __builtin_amdgcn_mfma_f32_16x16x32_bf16(a1, b1, acc, 0, 0, 0);
            if (lr < 3) {
#pragma unroll
                for (int r = 0; r < 4; ++r) {
                    const float v = acc[r] + bb;
                    const long long row = (long long)blockIdx.x * MPB + R + lg * 4 + r;
                    out[(long long)B + row * 3 + lr] = 1.f / (1.f + __expf(-v));
                }
            }
        }
    }
}

extern "C" void kernel_launch(void* const* d_in, const int* in_sizes, int n_in,
                              void* d_out, int out_size, void* d_ws, size_t ws_size,
                              hipStream_t stream) {
    const float* x    = (const float*)d_in[0];
    const float* dv   = (const float*)d_in[1];
    const int*   n    = (const int*)d_in[2];
    const float* grid = (const float*)d_in[3];
    const float* lat  = (const float*)d_in[4];
    const float* sw0  = (const float*)d_in[5];
    const float* sb0  = (const float*)d_in[6];
    const float* sw1  = (const float*)d_in[7];
    const float* sb1  = (const float*)d_in[8];
    const float* sw2  = (const float*)d_in[9];
    const float* sb2  = (const float*)d_in[10];
    const float* cw0  = (const float*)d_in[11];
    const float* cb0  = (const float*)d_in[12];
    const float* cw1  = (const float*)d_in[13];
    const float* cb1  = (const float*)d_in[14];
    const float* cw2  = (const float*)d_in[15];
    const float* cb2  = (const float*)d_in[16];
    const float* cw3  = (const float*)d_in[17];
    const float* cb3  = (const float*)d_in[18];

    const int B = in_sizes[2];           // 1048576; divisible by MPB=512
    const int nblocks = B / MPB;

    const int nent = 16 * TBL;                       // 8388608 table entries
    const size_t ws_need = (size_t)nent * 2;         // 16MB packed fp8 pairs

    if (ws_size >= ws_need) {
        grid_to_fp8<<<dim3((nent + 1023) / 1024), dim3(1024), 0, stream>>>(
            reinterpret_cast<const float2*>(grid), (unsigned short*)d_ws, nent);
        nerf_fused<1><<<dim3(nblocks), dim3(NTHR), 0, stream>>>(
            x, dv, n, (const void*)d_ws, lat,
            sw0, sb0, sw1, sb1, sw2, sb2,
            cw0, cb0, cw1, cb1, cw2, cb2, cw3, cb3,
            (float*)d_out, B);
    } else {
        nerf_fused<0><<<dim3(nblocks), dim3(NTHR), 0, stream>>>(
            x, dv, n, (const void*)grid, lat,
            sw0, sb0, sw1, sb1, sw2, sb2,
            cw0, cb0, cw1, cb1, cw2, cb2, cw3, cb3,
            (float*)d_out, B);
    }
}